// Round 7
// baseline (100.946 us; speedup 1.0000x reference)
//
#include <hip/hip_runtime.h>
#include <hip/hip_cooperative_groups.h>
#include <stdint.h>

namespace cg = cooperative_groups;

// CandidateFinder: binary-quantize (x>0), exact match on two 32-bit dim
// groups (union), gather first <=64 matching key indices per query, pad -1.
//
// R6 -> R7: ledger across R3-R6 pins the harness floor at ~47.5us and
// per-node overhead at ~0 beyond GPU time; R6's two tiny kernels + 2
// dispatch ramps + full inter-kernel drain cost ~16us vs ~5us of real work.
// This round: ONE cooperative kernel (256 blocks x 1024 thr, co-resident).
// Phase A packs 2 key rows/wave to d_ws; grid.sync(); phase B scans 2
// queries/wave with 16 branchless uint4 sig loads. Query rows are loaded
// and ballot-packed BEFORE phase A so their HBM latency hides under key
// packing. Fallback: R6's proven two-kernel path if coop launch rejected.
//
// wave=64 lanes <-> 64 dims: __ballot(v>0) IS the row's two 32-bit group
// signatures in canonical bit order. Matches emitted in ascending key order
// via ballot+popcount prefix = reference's sort-then-truncate.

#define LSEQ 2048
#define DDIM 64
#define KMAX 64

__device__ __forceinline__ void scan_and_emit(
    const uint2* __restrict__ ksig, int b,
    unsigned a0, unsigned g0, unsigned a1, unsigned g1,
    int* __restrict__ o0, int* __restrict__ o1, int lane) {
    // fast path: 16 uint4 loads, zero exec-mask toggles -> all in flight
    const uint4* kt = (const uint4*)(ksig + (size_t)b * LSEQ) + lane;
    unsigned long long acc0 = 0, acc1 = 0;
    int cnt0 = 0, cnt1 = 0;
#pragma unroll
    for (int i = 0; i < LSEQ / 128; ++i) {          // 16 iters, 128 keys each
        uint4 kv = kt[(size_t)i * 64];              // 1KB/wave, L1/L2-hot
        bool mA0 = (kv.x == a0) | (kv.y == g0);     // key 2*(i*64+lane)
        bool mB0 = (kv.z == a0) | (kv.w == g0);     // key 2*(i*64+lane)+1
        bool mA1 = (kv.x == a1) | (kv.y == g1);
        bool mB1 = (kv.z == a1) | (kv.w == g1);
        unsigned long long s;
        s = __ballot(mA0); acc0 |= s; cnt0 += __popcll(s);
        s = __ballot(mB0); acc0 |= s; cnt0 += __popcll(s);
        s = __ballot(mA1); acc1 |= s; cnt1 += __popcll(s);
        s = __ballot(mB1); acc1 |= s; cnt1 += __popcll(s);
    }
    if (acc0 | acc1) {                              // wave-uniform, p~2^-26:
        // exact ordered emit (ascending key index = sort-then-truncate)
        const uint2* ks = ksig + (size_t)b * LSEQ;
        unsigned long long below = (1ull << lane) - 1ull;
        for (int t = 0; t < 2; ++t) {
            unsigned qa = t ? a1 : a0, qg = t ? g1 : g0;
            int* ob = t ? o1 : o0;
            int c2 = 0;
            for (int c = 0; c < LSEQ / 64; ++c) {
                uint2 kv = ks[c * 64 + lane];
                bool m = (kv.x == qa) || (kv.y == qg);
                unsigned long long mask = __ballot(m);
                if (m) {
                    int pos = c2 + __popcll(mask & below);
                    if (pos < KMAX) ob[pos] = c * 64 + lane;
                }
                c2 += __popcll(mask);
            }
        }
    }
    // pad with -1 (KMAX == 64 lanes; disjoint from emitted positions)
    if (lane >= cnt0) o0[lane] = -1;
    if (lane >= cnt1) o1[lane] = -1;
}

// ---- cooperative single-launch kernel: grid = B*64 blocks x 1024 thr ----
__global__ __launch_bounds__(1024) void coop_kernel(
    const float* __restrict__ query, const float* __restrict__ key,
    uint2* __restrict__ ksig, int* __restrict__ out) {
    int wid  = (int)((blockIdx.x * blockDim.x + threadIdx.x) >> 6);
    int lane = threadIdx.x & 63;

    // queries first: their HBM latency hides under key packing below
    int q0 = wid * 2;
    const float* qp = query + (size_t)q0 * DDIM + lane;
    float qv0 = qp[0], qv1 = qp[DDIM];

    // phase A: pack this wave's 2 key rows
    int r0 = wid * 2;
    const float* kp = key + (size_t)r0 * DDIM + lane;
    float kv0 = kp[0], kv1 = kp[DDIM];
    unsigned long long km0 = __ballot(kv0 > 0.0f);
    unsigned long long km1 = __ballot(kv1 > 0.0f);
    if (lane == 0) {
        ksig[r0]     = make_uint2((unsigned)km0, (unsigned)(km0 >> 32));
        ksig[r0 + 1] = make_uint2((unsigned)km1, (unsigned)(km1 >> 32));
    }
    unsigned long long qm0 = __ballot(qv0 > 0.0f);
    unsigned long long qm1 = __ballot(qv1 > 0.0f);

    cg::this_grid().sync();

    // phase B: scan for this wave's 2 queries
    int b = q0 >> 11;                               // q0 / LSEQ
    int* o0 = out + (size_t)q0 * KMAX;
    scan_and_emit(ksig, b,
                  (unsigned)qm0, (unsigned)(qm0 >> 32),
                  (unsigned)qm1, (unsigned)(qm1 >> 32),
                  o0, o0 + KMAX, lane);
}

// ---- fallback: R6's proven two-kernel path ----
#define RPW 8
__global__ __launch_bounds__(256) void sig_kernel(
    const float* __restrict__ key, uint2* __restrict__ ksig, int nrows) {
    int wid  = (int)((blockIdx.x * blockDim.x + threadIdx.x) >> 6);
    int lane = threadIdx.x & 63;
    int row0 = wid * RPW;
    if (row0 >= nrows) return;
    const float* base = key + (size_t)row0 * DDIM + lane;
    float v[RPW];
#pragma unroll
    for (int u = 0; u < RPW; ++u) v[u] = base[(size_t)u * DDIM];
    unsigned long long m[RPW];
#pragma unroll
    for (int u = 0; u < RPW; ++u) m[u] = __ballot(v[u] > 0.0f);
    if (lane == 0) {
#pragma unroll
        for (int u = 0; u < RPW; ++u)
            ksig[row0 + u] = make_uint2((unsigned)m[u], (unsigned)(m[u] >> 32));
    }
}

__global__ __launch_bounds__(256) void match_kernel(
    const float* __restrict__ query, const uint2* __restrict__ ksig,
    int* __restrict__ out, int nq) {
    int wid  = (int)((blockIdx.x * blockDim.x + threadIdx.x) >> 6);
    int lane = threadIdx.x & 63;
    int q0 = wid * 2;
    if (q0 >= nq) return;
    int b = q0 >> 11;
    const float* qp = query + (size_t)q0 * DDIM + lane;
    float v0 = qp[0], v1 = qp[DDIM];
    unsigned long long qm0 = __ballot(v0 > 0.0f);
    unsigned long long qm1 = __ballot(v1 > 0.0f);
    int* o0 = out + (size_t)q0 * KMAX;
    scan_and_emit(ksig, b,
                  (unsigned)qm0, (unsigned)(qm0 >> 32),
                  (unsigned)qm1, (unsigned)(qm1 >> 32),
                  o0, o0 + KMAX, lane);
}

extern "C" void kernel_launch(void* const* d_in, const int* in_sizes, int n_in,
                              void* d_out, int out_size, void* d_ws, size_t ws_size,
                              hipStream_t stream) {
    const float* q = (const float*)d_in[0];
    const float* k = (const float*)d_in[1];
    // d_in[2] = head_idx, unused (inputs are already per-head)
    int* out = (int*)d_out;

    int total = in_sizes[0];             // B * L * D
    int B = total / (LSEQ * DDIM);       // = 4
    int nrows = B * LSEQ;                // 8192

    uint2* ksig = (uint2*)d_ws;          // 64 KB (ws is 256MB)

    // one cooperative launch: B*64 blocks x 1024 threads (16 waves/CU)
    void* args[] = {(void*)&q, (void*)&k, (void*)&ksig, (void*)&out};
    hipError_t err = hipLaunchCooperativeKernel(
        (void*)coop_kernel, dim3(B * 64), dim3(1024), args, 0, stream);
    if (err != hipSuccess) {
        // fallback: proven two-kernel path (same math, two nodes)
        int sig_waves = nrows / RPW;
        sig_kernel<<<sig_waves * 64 / 256, 256, 0, stream>>>(k, ksig, nrows);
        int match_waves = nrows / 2;
        match_kernel<<<match_waves * 64 / 256, 256, 0, stream>>>(q, ksig, out, nrows);
    }
}

// Round 9
// 98.258 us; speedup vs baseline: 1.0274x; 1.0274x over previous
//
#include <hip/hip_runtime.h>
#include <stdint.h>

// CandidateFinder: binary-quantize (x>0), exact match on two 32-bit dim
// groups (union), gather first <=64 matching key indices per query, pad -1.
//
// R8 -> R9: same design as R8 (single launch + lightweight flag barrier);
// only fix: __hip_atomic_fence doesn't exist in these headers -> use
// __builtin_amdgcn_fence(__ATOMIC_ACQUIRE, "agent").
//
// Design (from R8):
//  * 256 blocks x 1024 thr: capacity 2 blocks/CU -> all co-resident, and
//    every block produces BEFORE it spins -> deadlock-free by construction.
//  * sigs published via agent-scope RELAXED atomic stores (write-through to
//    the device coherence point; no reliance on cross-XCD L2 coherence).
//  * per-block flag = MAGIC (!= 0xAAAAAAAA harness poison -> no init pass),
//    RELEASE store after __syncthreads.
//  * consumers spin on their batch's 64 flags (64 lanes <-> 64 flags, one
//    relaxed agent load + ballot per round, s_sleep between), then ONE
//    agent-scope ACQUIRE fence (invalidates L1/L2 -> no stale poison
//    lines), then the R6 branchless uint4 scan (cached, L1-shared).
//
// wave=64 lanes <-> 64 dims: __ballot(v>0) IS the row's two 32-bit group
// signatures in canonical bit order. Matches emitted in ascending key order
// via ballot+popcount prefix = reference's sort-then-truncate.

#define LSEQ 2048
#define DDIM 64
#define KMAX 64
#define MAGIC 0x13572468u

__device__ __forceinline__ void scan_and_emit(
    const uint2* __restrict__ ksig, int b,
    unsigned a0, unsigned g0, unsigned a1, unsigned g1,
    int* __restrict__ o0, int* __restrict__ o1, int lane) {
    // fast path: 16 uint4 loads, zero exec-mask toggles -> all in flight
    const uint4* kt = (const uint4*)(ksig + (size_t)b * LSEQ) + lane;
    unsigned long long acc0 = 0, acc1 = 0;
    int cnt0 = 0, cnt1 = 0;
#pragma unroll
    for (int i = 0; i < LSEQ / 128; ++i) {          // 16 iters, 128 keys each
        uint4 kv = kt[(size_t)i * 64];              // 1KB/wave, L1/L2-hot
        bool mA0 = (kv.x == a0) | (kv.y == g0);     // key 2*(i*64+lane)
        bool mB0 = (kv.z == a0) | (kv.w == g0);     // key 2*(i*64+lane)+1
        bool mA1 = (kv.x == a1) | (kv.y == g1);
        bool mB1 = (kv.z == a1) | (kv.w == g1);
        unsigned long long s;
        s = __ballot(mA0); acc0 |= s; cnt0 += __popcll(s);
        s = __ballot(mB0); acc0 |= s; cnt0 += __popcll(s);
        s = __ballot(mA1); acc1 |= s; cnt1 += __popcll(s);
        s = __ballot(mB1); acc1 |= s; cnt1 += __popcll(s);
    }
    if (acc0 | acc1) {                              // wave-uniform, p~2^-26:
        // exact ordered emit (ascending key index = sort-then-truncate)
        const uint2* ks = ksig + (size_t)b * LSEQ;
        unsigned long long below = (1ull << lane) - 1ull;
        for (int t = 0; t < 2; ++t) {
            unsigned qa = t ? a1 : a0, qg = t ? g1 : g0;
            int* ob = t ? o1 : o0;
            int c2 = 0;
            for (int c = 0; c < LSEQ / 64; ++c) {
                uint2 kv = ks[c * 64 + lane];
                bool m = (kv.x == qa) || (kv.y == qg);
                unsigned long long mask = __ballot(m);
                if (m) {
                    int pos = c2 + __popcll(mask & below);
                    if (pos < KMAX) ob[pos] = c * 64 + lane;
                }
                c2 += __popcll(mask);
            }
        }
    }
    // pad with -1 (KMAX == 64 lanes; disjoint from emitted positions)
    if (lane >= cnt0) o0[lane] = -1;
    if (lane >= cnt1) o1[lane] = -1;
}

// ---- single launch: grid = B*64 blocks x 1024 thr, flag barrier in ws ----
__global__ __launch_bounds__(1024) void cand_kernel(
    const float* __restrict__ query, const float* __restrict__ key,
    uint2* __restrict__ ksig, unsigned* __restrict__ flags,
    int* __restrict__ out) {
    int wave = threadIdx.x >> 6;
    int lane = threadIdx.x & 63;
    int wid  = blockIdx.x * 16 + wave;
    int r0   = wid * 2;                 // 2 key rows AND 2 query rows / wave

    // 4 loads in one BB -> all in flight (one HBM round-trip)
    const float* kp = key   + (size_t)r0 * DDIM + lane;
    const float* qp = query + (size_t)r0 * DDIM + lane;
    float kv0 = kp[0], kv1 = kp[DDIM];
    float qv0 = qp[0], qv1 = qp[DDIM];
    unsigned long long km0 = __ballot(kv0 > 0.0f);
    unsigned long long km1 = __ballot(kv1 > 0.0f);
    unsigned long long qm0 = __ballot(qv0 > 0.0f);
    unsigned long long qm1 = __ballot(qv1 > 0.0f);

    // publish key sigs at agent scope (write-through; little-endian: low
    // 32 bits of the ballot == group-A word == .x of the uint2)
    if (lane == 0) {
        unsigned long long* kd = (unsigned long long*)(ksig + r0);
        __hip_atomic_store(&kd[0], km0, __ATOMIC_RELAXED, __HIP_MEMORY_SCOPE_AGENT);
        __hip_atomic_store(&kd[1], km1, __ATOMIC_RELAXED, __HIP_MEMORY_SCOPE_AGENT);
    }
    __syncthreads();                    // all 32 rows of this block published
    if (threadIdx.x == 0)
        __hip_atomic_store(&flags[blockIdx.x], MAGIC,
                           __ATOMIC_RELEASE, __HIP_MEMORY_SCOPE_AGENT);

    // spin on this batch's 64 flags (blocks [g*64, g*64+64) feed batch g)
    const unsigned* gf = flags + (blockIdx.x & ~63);
    for (;;) {
        unsigned f = __hip_atomic_load(&gf[lane],
                                       __ATOMIC_RELAXED, __HIP_MEMORY_SCOPE_AGENT);
        if (__ballot(f == MAGIC) == ~0ull) break;
        __builtin_amdgcn_s_sleep(1);
    }
    __builtin_amdgcn_fence(__ATOMIC_ACQUIRE, "agent");  // inv stale L1/L2

    // scan for this wave's 2 queries
    int b = r0 >> 11;                   // r0 / LSEQ
    int* o0 = out + (size_t)r0 * KMAX;
    scan_and_emit(ksig, b,
                  (unsigned)qm0, (unsigned)(qm0 >> 32),
                  (unsigned)qm1, (unsigned)(qm1 >> 32),
                  o0, o0 + KMAX, lane);
}

// ---- fallback (ws too small): R5's proven self-contained fused kernel ----
#define QPB  32
#define NW   16
#define GROUP 32
__global__ __launch_bounds__(1024) void fused_kernel(
    const float* __restrict__ query, const float* __restrict__ key,
    int* __restrict__ out) {
    __shared__ uint2 ks[LSEQ];
    const int bpb  = LSEQ / QPB;
    int b    = blockIdx.x / bpb;
    int qblk = blockIdx.x % bpb;
    int lane = threadIdx.x & 63;
    int wave = threadIdx.x >> 6;
    const float* kb = key + (size_t)b * LSEQ * DDIM;
    for (int g = 0; g < LSEQ / NW / GROUP; ++g) {
        float v[GROUP];
#pragma unroll
        for (int u = 0; u < GROUP; ++u)
            v[u] = kb[(size_t)(g * (NW * GROUP) + u * NW + wave) * DDIM + lane];
        unsigned long long m[GROUP];
#pragma unroll
        for (int u = 0; u < GROUP; ++u) m[u] = __ballot(v[u] > 0.0f);
        if (lane == 0) {
#pragma unroll
            for (int u = 0; u < GROUP; ++u)
                ks[g * (NW * GROUP) + u * NW + wave] =
                    make_uint2((unsigned)m[u], (unsigned)(m[u] >> 32));
        }
    }
    const float* qb = query + ((size_t)b * LSEQ + (size_t)qblk * QPB) * DDIM;
    int q0 = wave * 2;
    float v0 = qb[(size_t)q0 * DDIM + lane];
    float v1 = qb[(size_t)(q0 + 1) * DDIM + lane];
    unsigned long long m0 = __ballot(v0 > 0.0f);
    unsigned long long m1 = __ballot(v1 > 0.0f);
    __syncthreads();
    unsigned long long below = (1ull << lane) - 1ull;
    for (int t = 0; t < 2; ++t) {
        unsigned long long qm = t ? m1 : m0;
        unsigned q1 = (unsigned)qm, q2 = (unsigned)(qm >> 32);
        int* obase = out + ((size_t)b * LSEQ + (size_t)qblk * QPB + q0 + t) * KMAX;
        unsigned long long acc = 0;
        int cnt = 0;
#pragma unroll
        for (int c = 0; c < LSEQ / 64; ++c) {
            uint2 kv = ks[c * 64 + lane];
            bool m = (kv.x == q1) || (kv.y == q2);
            unsigned long long mask = __ballot(m);
            acc |= mask; cnt += __popcll(mask);
        }
        if (acc != 0) {
            int c2 = 0;
            for (int c = 0; c < LSEQ / 64; ++c) {
                uint2 kv = ks[c * 64 + lane];
                bool m = (kv.x == q1) || (kv.y == q2);
                unsigned long long mask = __ballot(m);
                if (m) {
                    int pos = c2 + __popcll(mask & below);
                    if (pos < KMAX) obase[pos] = c * 64 + lane;
                }
                c2 += __popcll(mask);
            }
        }
        if (lane >= cnt) obase[lane] = -1;
    }
}

extern "C" void kernel_launch(void* const* d_in, const int* in_sizes, int n_in,
                              void* d_out, int out_size, void* d_ws, size_t ws_size,
                              hipStream_t stream) {
    const float* q = (const float*)d_in[0];
    const float* k = (const float*)d_in[1];
    // d_in[2] = head_idx, unused (inputs are already per-head)
    int* out = (int*)d_out;

    int total = in_sizes[0];             // B * L * D
    int B = total / (LSEQ * DDIM);       // = 4
    int nrows = B * LSEQ;                // 8192

    size_t sig_bytes  = (size_t)nrows * sizeof(uint2);   // 64 KB
    size_t need       = sig_bytes + (size_t)(B * 64) * sizeof(unsigned);
    if (ws_size >= need) {
        uint2*    ksig  = (uint2*)d_ws;
        unsigned* flags = (unsigned*)((char*)d_ws + sig_bytes);
        cand_kernel<<<B * 64, 1024, 0, stream>>>(q, k, ksig, flags, out);
    } else {
        fused_kernel<<<B * (LSEQ / QPB), 1024, 0, stream>>>(q, k, out);
    }
}

// Round 10
// 81.414 us; speedup vs baseline: 1.2399x; 1.2069x over previous
//
#include <hip/hip_runtime.h>
#include <stdint.h>

// CandidateFinder: binary-quantize (x>0), exact match on two 32-bit dim
// groups (union), gather first <=64 matching key indices per query, pad -1.
//
// R9 -> R10: intra-kernel cross-block sync is a dead end on gfx950
// (flag barrier 44us, cg grid.sync ~38us — both >> a second graph node).
// The fused no-sync design's cost is LLC-traffic: R5 (QPB=32, 256 blocks)
// read 256x512KB = 128MB of redundant key slab ~= 25us. This round:
// QPB=128 -> 16 blocks/batch -> 64 blocks -> 32MB total (~5us), per-block
// ingest 512KB || across 64 CUs (~4us), scan ~1us. ONE launch, no d_ws,
// no sync. Known-correct R5 structure; only QPB + scan width changed.
//
// wave=64 lanes <-> 64 dims: __ballot(v>0) IS the row's two 32-bit group
// signatures in canonical bit order. Matches emitted in ascending key order
// via ballot+popcount prefix = reference's sort-then-truncate.

#define LSEQ 2048
#define DDIM 64
#define KMAX 64
#define QPB  128  // queries per block -> grid = B * 16 = 64 blocks
#define NW   16   // waves per block (1024 threads)
#define GROUP 32  // key rows loaded branch-free per wave per pass
#define QG   8    // queries per wave (NW * QG == QPB)

__global__ __launch_bounds__(1024) void fused_kernel(
    const float* __restrict__ query, const float* __restrict__ key,
    int* __restrict__ out) {
    __shared__ uint2 ks[LSEQ];          // 16 KB: this batch's key signatures

    const int bpb  = LSEQ / QPB;        // 16 blocks per batch
    int b    = blockIdx.x / bpb;
    int qblk = blockIdx.x % bpb;
    int lane = threadIdx.x & 63;
    int wave = threadIdx.x >> 6;

    // ---- pack all 2048 key rows: 128 rows/wave in 4 branch-free groups ----
    const float* kb = key + (size_t)b * LSEQ * DDIM;
    for (int g = 0; g < LSEQ / NW / GROUP; ++g) {   // 4 groups
        float v[GROUP];
#pragma unroll
        for (int u = 0; u < GROUP; ++u)             // 32 loads, one BB,
            v[u] = kb[(size_t)(g * (NW * GROUP) + u * NW + wave) * DDIM + lane];
        unsigned long long m[GROUP];
#pragma unroll
        for (int u = 0; u < GROUP; ++u)             // branchless (scalar dst)
            m[u] = __ballot(v[u] > 0.0f);
        if (lane == 0) {                            // ONE exec toggle / group
#pragma unroll
            for (int u = 0; u < GROUP; ++u)
                ks[g * (NW * GROUP) + u * NW + wave] =
                    make_uint2((unsigned)m[u], (unsigned)(m[u] >> 32));
        }
    }

    // ---- this wave's 8 query signatures (branch-free load group) ----
    const float* qb = query + ((size_t)b * LSEQ + (size_t)qblk * QPB) * DDIM;
    int q0 = wave * QG;                             // local query idx base
    float qv[QG];
#pragma unroll
    for (int u = 0; u < QG; ++u)                    // 8 loads, one BB
        qv[u] = qb[(size_t)(q0 + u) * DDIM + lane];
    unsigned long long qm[QG];
#pragma unroll
    for (int u = 0; u < QG; ++u)
        qm[u] = __ballot(qv[u] > 0.0f);

    __syncthreads();

    // ---- scan: 8 queries/wave, 16 uint4 LDS loads each (2 keys/lane) ----
    const uint4* kt4 = (const uint4*)ks;
    unsigned long long below = (1ull << lane) - 1ull;
    for (int t = 0; t < QG; ++t) {
        unsigned qa = (unsigned)qm[t], qg = (unsigned)(qm[t] >> 32);
        int* ob = out + ((size_t)b * LSEQ + (size_t)qblk * QPB + q0 + t) * KMAX;

        // fast path: fully branchless, 16 ds_read_b128 back-to-back
        unsigned long long acc = 0;
        int cnt = 0;
#pragma unroll
        for (int i = 0; i < LSEQ / 128; ++i) {      // 16 iters, 128 keys
            uint4 kv = kt4[i * 64 + lane];
            bool mA = (kv.x == qa) | (kv.y == qg);  // key 2*(i*64+lane)
            bool mB = (kv.z == qa) | (kv.w == qg);  // key 2*(i*64+lane)+1
            unsigned long long s;
            s = __ballot(mA); acc |= s; cnt += __popcll(s);
            s = __ballot(mB); acc |= s; cnt += __popcll(s);
        }

        if (acc != 0) {                             // wave-uniform, p~2^-26:
            // exact ordered emit (ascending key idx = sort-then-truncate)
            int c2 = 0;
            for (int c = 0; c < LSEQ / 64; ++c) {
                uint2 kv = ks[c * 64 + lane];
                bool m = (kv.x == qa) || (kv.y == qg);
                unsigned long long mask = __ballot(m);
                if (m) {
                    int pos = c2 + __popcll(mask & below);
                    if (pos < KMAX) ob[pos] = c * 64 + lane;
                }
                c2 += __popcll(mask);
            }
        }
        // pad remaining slots with -1 (64 lanes == KMAX; disjoint vs matches)
        if (lane >= cnt) ob[lane] = -1;
    }
}

extern "C" void kernel_launch(void* const* d_in, const int* in_sizes, int n_in,
                              void* d_out, int out_size, void* d_ws, size_t ws_size,
                              hipStream_t stream) {
    const float* q = (const float*)d_in[0];
    const float* k = (const float*)d_in[1];
    // d_in[2] = head_idx, unused (inputs are already per-head)
    int* out = (int*)d_out;

    int total = in_sizes[0];             // B * L * D
    int B = total / (LSEQ * DDIM);       // = 4

    fused_kernel<<<B * (LSEQ / QPB), 1024, 0, stream>>>(q, k, out);
}

// Round 11
// 63.145 us; speedup vs baseline: 1.5986x; 1.2893x over previous
//
#include <hip/hip_runtime.h>
#include <stdint.h>

// CandidateFinder: binary-quantize (x>0), exact match on two 32-bit dim
// groups (union), gather first <=64 matching key indices per query, pad -1.
//
// R10 -> R11: fused family is capped ~25us (measured both ends: nb=64
// blocks/batch -> 25us LLC-bound on redundant raw key reads; nb=16 -> 34us
// scan-bound on 64 CUs). Two-node R6 (16us over floor) wins, and its real
// cost was mislabeled: match read the 16KB sig table from GLOBAL per wave
// (4096 x 16KB = 64MB L2/LLC ~= 12.5us, L1 thrashed by 4 batches/CU).
// Fix: stage sigs in LDS once per BLOCK (1 uint4 load + ds_write per
// thread = 16KB/block, 4MB total), scan 2 q/wave from LDS.
//
// wave=64 lanes <-> 64 dims: __ballot(v>0) IS the row's two 32-bit group
// signatures in canonical bit order. Matches emitted in ascending key order
// via ballot+popcount prefix = reference's sort-then-truncate.

#define LSEQ 2048
#define DDIM 64
#define KMAX 64
#define RPW  8    // rows packed per wave in sig kernel
#define MQPB 32   // queries per match block (1024 thr, 16 waves, 2 q/wave)

// Phase 1: pack key sign bits (R6's proven kernel, unchanged).
__global__ __launch_bounds__(256) void sig_kernel(
    const float* __restrict__ key, uint2* __restrict__ ksig, int nrows) {
    int wid  = (int)((blockIdx.x * blockDim.x + threadIdx.x) >> 6);
    int lane = threadIdx.x & 63;
    int row0 = wid * RPW;
    if (row0 >= nrows) return;                      // wave-uniform
    const float* base = key + (size_t)row0 * DDIM + lane;
    float v[RPW];
#pragma unroll
    for (int u = 0; u < RPW; ++u)                   // 8 loads, one BB
        v[u] = base[(size_t)u * DDIM];              // 256B/wave coalesced
    unsigned long long m[RPW];
#pragma unroll
    for (int u = 0; u < RPW; ++u)
        m[u] = __ballot(v[u] > 0.0f);               // branchless, scalar dst
    if (lane == 0) {                                // one exec toggle
#pragma unroll
        for (int u = 0; u < RPW; ++u)               // 64B contiguous
            ksig[row0 + u] = make_uint2((unsigned)m[u], (unsigned)(m[u] >> 32));
    }
}

// Phase 2: 256 blocks x 1024 thr; block stages its batch's 16KB sig table
// in LDS (one uint4 per thread), then 16 waves scan 2 queries each.
__global__ __launch_bounds__(1024) void match_kernel(
    const float* __restrict__ query, const uint2* __restrict__ ksig,
    int* __restrict__ out) {
    __shared__ uint4 sh[LSEQ / 2];      // 16 KB (uint4 = 2 key sigs)

    const int bpb = LSEQ / MQPB;        // 64 blocks per batch
    int b    = blockIdx.x / bpb;
    int qblk = blockIdx.x % bpb;
    int lane = threadIdx.x & 63;
    int wave = threadIdx.x >> 6;

    // stage: 1024 threads x 16B = whole table, one global round-trip
    const uint4* gt = (const uint4*)(ksig + (size_t)b * LSEQ);
    sh[threadIdx.x] = gt[threadIdx.x];

    // this wave's 2 query signatures (overlaps with staging latency)
    int q0 = b * LSEQ + qblk * MQPB + wave * 2;     // global query idx
    const float* qp = query + (size_t)q0 * DDIM + lane;
    float v0 = qp[0], v1 = qp[DDIM];
    unsigned long long qm0 = __ballot(v0 > 0.0f);
    unsigned long long qm1 = __ballot(v1 > 0.0f);

    __syncthreads();

    unsigned long long below = (1ull << lane) - 1ull;
    const uint2* ks2 = (const uint2*)sh;
    for (int t = 0; t < 2; ++t) {
        unsigned long long qm = t ? qm1 : qm0;
        unsigned qa = (unsigned)qm, qg = (unsigned)(qm >> 32);
        int* ob = out + (size_t)(q0 + t) * KMAX;

        // fast path: fully branchless, 16 ds_read_b128 back-to-back
        unsigned long long acc = 0;
        int cnt = 0;
#pragma unroll
        for (int i = 0; i < LSEQ / 128; ++i) {      // 16 iters, 128 keys
            uint4 kv = sh[i * 64 + lane];
            bool mA = (kv.x == qa) | (kv.y == qg);  // key 2*(i*64+lane)
            bool mB = (kv.z == qa) | (kv.w == qg);  // key 2*(i*64+lane)+1
            unsigned long long s;
            s = __ballot(mA); acc |= s; cnt += __popcll(s);
            s = __ballot(mB); acc |= s; cnt += __popcll(s);
        }

        if (acc != 0) {                             // wave-uniform, p~2^-26:
            // exact ordered emit (ascending key idx = sort-then-truncate)
            int c2 = 0;
            for (int c = 0; c < LSEQ / 64; ++c) {
                uint2 kv = ks2[c * 64 + lane];
                bool m = (kv.x == qa) || (kv.y == qg);
                unsigned long long mask = __ballot(m);
                if (m) {
                    int pos = c2 + __popcll(mask & below);
                    if (pos < KMAX) ob[pos] = c * 64 + lane;
                }
                c2 += __popcll(mask);
            }
        }
        // pad remaining slots with -1 (64 lanes == KMAX; disjoint vs matches)
        if (lane >= cnt) ob[lane] = -1;
    }
}

// Fallback (ws too small): R5's proven self-contained fused kernel.
#define QPB  32
#define NW   16
#define GROUP 32
__global__ __launch_bounds__(1024) void fused_kernel(
    const float* __restrict__ query, const float* __restrict__ key,
    int* __restrict__ out) {
    __shared__ uint2 ks[LSEQ];
    const int bpb  = LSEQ / QPB;
    int b    = blockIdx.x / bpb;
    int qblk = blockIdx.x % bpb;
    int lane = threadIdx.x & 63;
    int wave = threadIdx.x >> 6;
    const float* kb = key + (size_t)b * LSEQ * DDIM;
    for (int g = 0; g < LSEQ / NW / GROUP; ++g) {
        float v[GROUP];
#pragma unroll
        for (int u = 0; u < GROUP; ++u)
            v[u] = kb[(size_t)(g * (NW * GROUP) + u * NW + wave) * DDIM + lane];
        unsigned long long m[GROUP];
#pragma unroll
        for (int u = 0; u < GROUP; ++u) m[u] = __ballot(v[u] > 0.0f);
        if (lane == 0) {
#pragma unroll
            for (int u = 0; u < GROUP; ++u)
                ks[g * (NW * GROUP) + u * NW + wave] =
                    make_uint2((unsigned)m[u], (unsigned)(m[u] >> 32));
        }
    }
    const float* qb = query + ((size_t)b * LSEQ + (size_t)qblk * QPB) * DDIM;
    int q0 = wave * 2;
    float v0 = qb[(size_t)q0 * DDIM + lane];
    float v1 = qb[(size_t)(q0 + 1) * DDIM + lane];
    unsigned long long m0 = __ballot(v0 > 0.0f);
    unsigned long long m1 = __ballot(v1 > 0.0f);
    __syncthreads();
    unsigned long long below = (1ull << lane) - 1ull;
    for (int t = 0; t < 2; ++t) {
        unsigned long long qm = t ? m1 : m0;
        unsigned q1 = (unsigned)qm, q2 = (unsigned)(qm >> 32);
        int* obase = out + ((size_t)b * LSEQ + (size_t)qblk * QPB + q0 + t) * KMAX;
        unsigned long long acc = 0;
        int cnt = 0;
#pragma unroll
        for (int c = 0; c < LSEQ / 64; ++c) {
            uint2 kv = ks[c * 64 + lane];
            bool m = (kv.x == q1) || (kv.y == q2);
            unsigned long long mask = __ballot(m);
            acc |= mask; cnt += __popcll(mask);
        }
        if (acc != 0) {
            int c2 = 0;
            for (int c = 0; c < LSEQ / 64; ++c) {
                uint2 kv = ks[c * 64 + lane];
                bool m = (kv.x == q1) || (kv.y == q2);
                unsigned long long mask = __ballot(m);
                if (m) {
                    int pos = c2 + __popcll(mask & below);
                    if (pos < KMAX) obase[pos] = c * 64 + lane;
                }
                c2 += __popcll(mask);
            }
        }
        if (lane >= cnt) obase[lane] = -1;
    }
}

extern "C" void kernel_launch(void* const* d_in, const int* in_sizes, int n_in,
                              void* d_out, int out_size, void* d_ws, size_t ws_size,
                              hipStream_t stream) {
    const float* q = (const float*)d_in[0];
    const float* k = (const float*)d_in[1];
    // d_in[2] = head_idx, unused (inputs are already per-head)
    int* out = (int*)d_out;

    int total = in_sizes[0];             // B * L * D
    int B = total / (LSEQ * DDIM);       // = 4
    int nrows = B * LSEQ;                // 8192

    if (ws_size >= (size_t)nrows * sizeof(uint2)) {
        uint2* ksig = (uint2*)d_ws;
        sig_kernel<<<nrows / RPW * 64 / 256, 256, 0, stream>>>(k, ksig, nrows);
        match_kernel<<<nrows / MQPB, 1024, 0, stream>>>(q, ksig, out);
    } else {
        fused_kernel<<<B * (LSEQ / QPB), 1024, 0, stream>>>(q, k, out);
    }
}